// Round 12
// baseline (102.945 us; speedup 1.0000x reference)
//
#include <hip/hip_runtime.h>

#define S_DIM 20
#define NSTEP 19     // S_DIM - 1 compute steps
#define EMB   64
#define GSTR  36     // uint32 words/ped-row: 0..31 bf16 gm_sum, 4 pad
#define MAXP  128

typedef __attribute__((ext_vector_type(8))) short bf16x8;
typedef __attribute__((ext_vector_type(4))) float f32x4;

__device__ __forceinline__ uint32_t pk_bf16(float lo, float hi) {
    uint32_t r;
    asm("v_cvt_pk_bf16_f32 %0, %1, %2" : "=v"(r) : "v"(lo), "v"(hi));
    return r;
}
__device__ __forceinline__ short bf16s(float v) { return (short)(pk_bf16(v, v) & 0xffffu); }
__device__ __forceinline__ float unbf16(uint32_t lo16) {
    union { uint32_t u; float f; } c; c.u = lo16 << 16; return c.f;
}
__device__ __forceinline__ float asf(uint32_t u) {
    union { uint32_t u; float f; } c; c.u = u; return c.f;
}

__global__ __launch_bounds__(256, 2) void pfa_kernel(
    const float* __restrict__ nodes_abs,   // (S,N,2)
    const float* __restrict__ seq_list,    // (S,N)
    const int*   __restrict__ pednum,      // (B)
    const float* __restrict__ W_in,        // (2,EMB)
    const float* __restrict__ W_gm,        // (EMB,EMB)
    const float* __restrict__ b_h,         // (EMB)
    const float* __restrict__ W_out,       // (EMB,2)
    const float* __restrict__ b_out,       // (2)
    float*       __restrict__ out,         // (S,N,2)
    int N, int B)
{
    const int blk  = blockIdx.x;
    const int sc   = blk >> 1;          // scene
    const int half = blk & 1;           // which 4 row-blocks
    const int t    = threadIdx.x;
    const int lane = t & 63;
    const int w    = t >> 6;            // 4 waves, one row-block each
    const int l15  = lane & 15;
    const int hi   = lane >> 4;

    __shared__ __attribute__((aligned(16))) uint32_t G[4 * 16 * GSTR];  // 9216 B, wave-private slices
    __shared__ uint32_t masks[MAXP];
    __shared__ float2   cxy[NSTEP];

    // ---- scene start: per-wave redundant prefix sum of pednum ----
    int partial = 0;
    for (int i = lane; i < sc; i += 64) partial += pednum[i];
    #pragma unroll
    for (int off = 32; off; off >>= 1) partial += __shfl_xor(partial, off, 64);
    const int start = partial;
    const int P = min(pednum[sc], MAXP);
    const int q = (P + 7) >> 3;         // peds per row-block (8 rb across 2 blocks)

    // ---- zero own G slice (wave-private) ----
    {
        uint4* g4 = (uint4*)&G[w * 16 * GSTR];
        for (int i = lane; i < 16 * GSTR / 4; i += 64)
            g4[i] = make_uint4(0u, 0u, 0u, 0u);
    }

    // ---- constant A-fragments ----
    bf16x8 agm[4][2];
    #pragma unroll
    for (int m = 0; m < 4; ++m)
        #pragma unroll
        for (int T = 0; T < 2; ++T)
            #pragma unroll
            for (int e = 0; e < 8; ++e)
                agm[m][T][e] = bf16s(W_gm[(32*T + 8*hi + e) * EMB + 16*m + l15]);

    bf16x8 aaug[4];
    #pragma unroll
    for (int m = 0; m < 4; ++m) {
        bf16x8 a = {0,0,0,0,0,0,0,0};
        if (hi == 0) {
            const int j = 16*m + l15;
            const float w0 = W_in[j], w1 = W_in[EMB + j], bh = b_h[j];
            const short w0h = bf16s(w0); const short w0l = bf16s(w0 - unbf16((uint16_t)w0h));
            const short w1h = bf16s(w1); const short w1l = bf16s(w1 - unbf16((uint16_t)w1h));
            const short bhh = bf16s(bh); const short bhl = bf16s(bh - unbf16((uint16_t)bhh));
            a[0]=w0h; a[1]=w0l; a[2]=w0h; a[3]=w1h; a[4]=w1l; a[5]=w1h; a[6]=bhh; a[7]=bhl;
        }
        aaug[m] = a;
    }

    // W_out packed bf16 pairs: j = 16m+4hi+rr
    uint32_t wopk[4][4];
    #pragma unroll
    for (int m = 0; m < 4; ++m)
        #pragma unroll
        for (int rr = 0; rr < 4; ++rr) {
            const float2 v = *(const float2*)&W_out[(16*m + 4*hi + rr) * 2];
            wopk[m][rr] = pk_bf16(v.x, v.y);
        }
    const float bo0 = b_out[0], bo1 = b_out[1];

    // ---- Phase 1: per-ped presence bitmask (prefix-AND over steps) ----
    if (t < P) {
        uint32_t m = 0; bool alive = true;
        #pragma unroll
        for (int f = 0; f < NSTEP; ++f) {
            alive = alive && (seq_list[(size_t)f * N + start + t] > 0.0f);
            m |= (alive ? 1u : 0u) << f;
        }
        masks[t] = m;
    }
    __syncthreads();

    // ---- Phase 2: per-step scene centers (wave w handles f = w, w+4, ...) ----
    for (int f = w; f < NSTEP; f += 4) {
        float cnt = 0.f, sx = 0.f, sy = 0.f;
        for (int p = lane; p < P; p += 64) {
            const float mf = (float)((masks[p] >> f) & 1u);
            const float2 a = *(const float2*)&nodes_abs[((size_t)f * N + start + p) * 2];
            cnt += mf; sx = fmaf(a.x, mf, sx); sy = fmaf(a.y, mf, sy);
        }
        #pragma unroll
        for (int off = 32; off; off >>= 1) {
            cnt += __shfl_xor(cnt, off, 64);
            sx  += __shfl_xor(sx , off, 64);
            sy  += __shfl_xor(sy , off, 64);
        }
        if (lane == 0) {
            const float ic = __builtin_amdgcn_rcpf(fmaxf(cnt, 1.0f));
            cxy[f] = make_float2(sx * ic, sy * ic);
        }
    }
    __syncthreads();

    // ---- Phase 3: sequential loop — no barriers, 1 LDS round-trip per step ----
    const int  rb = half * 4 + w;       // this wave's row-block (0..7)
    const int  pd = rb * q + l15;
    const bool vr = (l15 < q) && (pd < P);
    const int  gi = start + (vr ? pd : 0);
    const uint32_t mk = vr ? masks[pd] : 0u;
    float2 ab = *(const float2*)&nodes_abs[(size_t)gi * 2];

    uint32_t* const Grow = &G[(w * 16 + l15) * GSTR];
    const bool h0 = (hi == 0);

    f32x4 gm[4];
    const f32x4 zero4 = {0.f, 0.f, 0.f, 0.f};
    #pragma unroll
    for (int m = 0; m < 4; ++m) gm[m] = zero4;

    #pragma unroll 1
    for (int f = 0; f < NSTEP; ++f) {
        const float2 c = cxy[f];
        const float mf  = (float)((mk >> f) & 1u);
        const float cxd = ab.x - c.x;
        const float cyd = ab.y - c.y;
        // prefetch next step's coords (row f+1 always exists: S_DIM rows)
        ab = *(const float2*)&nodes_abs[((size_t)(f + 1) * N + gi) * 2];

        // aug B-fragment in registers (k rows 0..7 live in hi==0 lanes)
        const uint32_t e0 = pk_bf16(cxd, cxd);
        const float    cxl = cxd - unbf16(e0 & 0xffffu);
        const uint32_t ey = pk_bf16(cyd, cyd);
        const float    cyl = cyd - unbf16(ey & 0xffffu);
        const uint32_t e1 = pk_bf16(cxl, cyd);
        const uint32_t e2 = pk_bf16(cyd, cyl);
        union { uint32_t u[4]; bf16x8 v; } b2u;
        b2u.u[0] = h0 ? e0 : 0u;
        b2u.u[1] = h0 ? e1 : 0u;
        b2u.u[2] = h0 ? e2 : 0u;
        b2u.u[3] = h0 ? 0x3f803f80u : 0u;

        // S_{f-1} B-fragments (bf16 raw gm_sum, words 0..31 of own row)
        const bf16x8 B0 = *(const bf16x8*)&Grow[ 0 + 4*hi];
        const bf16x8 B1 = *(const bf16x8*)&Grow[16 + 4*hi];

        const float invf = __builtin_amdgcn_rcpf((float)(f ? f : 1));   // gm_mean divisor for THIS step
        const float m2 = -2.0f * mf;

        float o0 = 0.0f, o1 = 0.0f;
        #pragma unroll
        for (int m = 0; m < 4; ++m) {
            f32x4 ag = zero4;   // gm_sum @ W_gm part (scaled by invf at combine)
            ag = __builtin_amdgcn_mfma_f32_16x16x32_bf16(agm[m][0], B0, ag, 0, 0, 0);
            ag = __builtin_amdgcn_mfma_f32_16x16x32_bf16(agm[m][1], B1, ag, 0, 0, 0);
            f32x4 aa = zero4;   // coord @ W_in + b_h part
            aa = __builtin_amdgcn_mfma_f32_16x16x32_bf16(aaug[m], b2u.v, aa, 0, 0, 0);

            f32x4 h4;
            #pragma unroll
            for (int rr = 0; rr < 4; ++rr) {
                const float x  = fmaf(ag[rr], invf, aa[rr]);
                const float e  = __expf(2.0f * x);
                const float tt = __builtin_amdgcn_rcpf(e + 1.0f);
                h4[rr] = fmaf(tt, m2, mf);          // mf * tanh(x)
                o0 = fmaf(h4[rr], asf(wopk[m][rr] << 16),         o0);
                o1 = fmaf(h4[rr], asf(wopk[m][rr] & 0xffff0000u), o1);
            }
            gm[m] += h4;
            // write S_f (raw gm_sum, bf16) — the ONLY next-step dependency
            const uint32_t p0 = pk_bf16(gm[m][0], gm[m][1]);
            const uint32_t p1 = pk_bf16(gm[m][2], gm[m][3]);
            *(uint2*)&Grow[8*m + 2*hi] = make_uint2(p0, p1);
        }

        // out = (h @ W_out + b_out) * mf — fp32 h, off the critical path
        o0 += __shfl_xor(o0, 16, 64);  o0 += __shfl_xor(o0, 32, 64);
        o1 += __shfl_xor(o1, 16, 64);  o1 += __shfl_xor(o1, 32, 64);
        if (h0 && vr) {
            float2 o;
            o.x = (o0 + bo0) * mf;
            o.y = (o1 + bo1) * mf;
            *(float2*)&out[((size_t)f * N + gi) * 2] = o;
        }
    }

    // ---- final step S-1: zeros (both half-blocks write; benign duplicate) ----
    if (t < P) {
        const size_t o = ((size_t)(S_DIM - 1) * N + start + t) * 2;
        out[o] = 0.0f; out[o + 1] = 0.0f;
    }
}

extern "C" void kernel_launch(void* const* d_in, const int* in_sizes, int n_in,
                              void* d_out, int out_size, void* d_ws, size_t ws_size,
                              hipStream_t stream) {
    const float* nodes_abs = (const float*)d_in[0];
    const float* seq_list  = (const float*)d_in[3];
    const int*   pednum    = (const int*)  d_in[5];
    const float* W_in      = (const float*)d_in[6];
    const float* W_gm      = (const float*)d_in[7];
    const float* b_h       = (const float*)d_in[8];
    const float* W_out     = (const float*)d_in[9];
    const float* b_out     = (const float*)d_in[10];
    float*       out       = (float*)d_out;

    const int N = in_sizes[3] / S_DIM;
    const int B = in_sizes[5];

    pfa_kernel<<<2 * B, 256, 0, stream>>>(nodes_abs, seq_list, pednum,
                                          W_in, W_gm, b_h, W_out, b_out,
                                          out, N, B);
}

// Round 13
// 89.787 us; speedup vs baseline: 1.1465x; 1.1465x over previous
//
#include <hip/hip_runtime.h>

#define S_DIM 20
#define NSTEP 19     // S_DIM - 1 compute steps
#define EMB   64
#define GSTR  36     // uint32 words/ped-row: 0..31 bf16 gm_sum, 4 pad
#define MAXP  128

typedef __attribute__((ext_vector_type(8))) short bf16x8;
typedef __attribute__((ext_vector_type(4))) short bf16x4;
typedef __attribute__((ext_vector_type(4))) float f32x4;

__device__ __forceinline__ uint32_t pk_bf16(float lo, float hi) {
    uint32_t r;
    asm("v_cvt_pk_bf16_f32 %0, %1, %2" : "=v"(r) : "v"(lo), "v"(hi));
    return r;
}
__device__ __forceinline__ short bf16s(float v) { return (short)(pk_bf16(v, v) & 0xffffu); }
__device__ __forceinline__ float unbf16(uint32_t lo16) {
    union { uint32_t u; float f; } c; c.u = lo16 << 16; return c.f;
}
__device__ __forceinline__ float asf(uint32_t u) {
    union { uint32_t u; float f; } c; c.u = u; return c.f;
}

// K=16 bf16 MFMA (A/B = 2 VGPRs each) — halves the aug-fragment register cost.
__device__ __forceinline__ f32x4 mfma16(bf16x4 a, bf16x4 b, f32x4 c) {
#if __has_builtin(__builtin_amdgcn_mfma_f32_16x16x16bf16_1k)
    return __builtin_amdgcn_mfma_f32_16x16x16bf16_1k(a, b, c, 0, 0, 0);
#else
    asm("v_mfma_f32_16x16x16_bf16 %0, %1, %2, %0" : "+v"(c) : "v"(a), "v"(b));
    return c;
#endif
}

__global__ __launch_bounds__(512, 4) void pfa_kernel(
    const float* __restrict__ nodes_abs,   // (S,N,2)
    const float* __restrict__ seq_list,    // (S,N)
    const int*   __restrict__ pednum,      // (B)
    const float* __restrict__ W_in,        // (2,EMB)
    const float* __restrict__ W_gm,        // (EMB,EMB)
    const float* __restrict__ b_h,         // (EMB)
    const float* __restrict__ W_out,       // (EMB,2)
    const float* __restrict__ b_out,       // (2)
    float*       __restrict__ out,         // (S,N,2)
    int N, int B)
{
    const int b    = blockIdx.x;
    const int t    = threadIdx.x;
    const int lane = t & 63;
    const int w    = t >> 6;            // 8 waves, one row-block each
    const int l15  = lane & 15;
    const int hi   = lane >> 4;

    __shared__ __attribute__((aligned(16))) uint32_t G[8 * 16 * GSTR];  // 18432 B, wave-private slices
    __shared__ uint32_t masks[MAXP];
    __shared__ float2   cxy[NSTEP];

    // ---- scene start: per-wave redundant prefix sum of pednum ----
    int partial = 0;
    for (int i = lane; i < b; i += 64) partial += pednum[i];
    #pragma unroll
    for (int off = 32; off; off >>= 1) partial += __shfl_xor(partial, off, 64);
    const int start = partial;
    const int P = min(pednum[b], MAXP);
    const int q = (P + 7) >> 3;         // peds per row-block (8 rb)

    // ---- zero own G slice (wave-private) ----
    {
        uint4* g4 = (uint4*)&G[w * 16 * GSTR];
        for (int i = lane; i < 16 * GSTR / 4; i += 64)
            g4[i] = make_uint4(0u, 0u, 0u, 0u);
    }

    // ---- constant A-fragments ----
    // gm-MFMA (K=32 ×2): A-frag row j=16m+l15, k=32T+8hi+e
    bf16x8 agm[4][2];
    #pragma unroll
    for (int m = 0; m < 4; ++m)
        #pragma unroll
        for (int T = 0; T < 2; ++T)
            #pragma unroll
            for (int e = 0; e < 8; ++e)
                agm[m][T][e] = bf16s(W_gm[(32*T + 8*hi + e) * EMB + 16*m + l15]);

    // aug A-tile, K=16 layout (k = 4*hi + e): rows 0..7 used.
    // k0..3 (hi==0): [w0h, w0l, w0h, w1h]; k4..7 (hi==1): [w1l, w1h, bhh, bhl]
    bf16x4 aaug[4];
    #pragma unroll
    for (int m = 0; m < 4; ++m) {
        bf16x4 a = {0, 0, 0, 0};
        const int j = 16*m + l15;
        const float w0 = W_in[j], w1 = W_in[EMB + j], bh = b_h[j];
        const short w0h = bf16s(w0); const short w0l = bf16s(w0 - unbf16((uint16_t)w0h));
        const short w1h = bf16s(w1); const short w1l = bf16s(w1 - unbf16((uint16_t)w1h));
        const short bhh = bf16s(bh); const short bhl = bf16s(bh - unbf16((uint16_t)bhh));
        if (hi == 0)      { a[0] = w0h; a[1] = w0l; a[2] = w0h; a[3] = w1h; }
        else if (hi == 1) { a[0] = w1l; a[1] = w1h; a[2] = bhh; a[3] = bhl; }
        aaug[m] = a;
    }

    // W_out packed bf16 pairs: j = 16m+4hi+rr
    uint32_t wopk[4][4];
    #pragma unroll
    for (int m = 0; m < 4; ++m)
        #pragma unroll
        for (int rr = 0; rr < 4; ++rr) {
            const float2 v = *(const float2*)&W_out[(16*m + 4*hi + rr) * 2];
            wopk[m][rr] = pk_bf16(v.x, v.y);
        }
    const float bo0 = b_out[0], bo1 = b_out[1];

    // ---- Phase 1: per-ped presence bitmask (prefix-AND over steps) ----
    if (t < P) {
        uint32_t m = 0; bool alive = true;
        #pragma unroll
        for (int f = 0; f < NSTEP; ++f) {
            alive = alive && (seq_list[(size_t)f * N + start + t] > 0.0f);
            m |= (alive ? 1u : 0u) << f;
        }
        masks[t] = m;
    }
    __syncthreads();

    // ---- Phase 2: per-step scene centers (wave w handles f = w, w+8, ...) ----
    for (int f = w; f < NSTEP; f += 8) {
        float cnt = 0.f, sx = 0.f, sy = 0.f;
        for (int p = lane; p < P; p += 64) {
            const float mf = (float)((masks[p] >> f) & 1u);
            const float2 a = *(const float2*)&nodes_abs[((size_t)f * N + start + p) * 2];
            cnt += mf; sx = fmaf(a.x, mf, sx); sy = fmaf(a.y, mf, sy);
        }
        #pragma unroll
        for (int off = 32; off; off >>= 1) {
            cnt += __shfl_xor(cnt, off, 64);
            sx  += __shfl_xor(sx , off, 64);
            sy  += __shfl_xor(sy , off, 64);
        }
        if (lane == 0) {
            const float ic = __builtin_amdgcn_rcpf(fmaxf(cnt, 1.0f));
            cxy[f] = make_float2(sx * ic, sy * ic);
        }
    }
    __syncthreads();

    // ---- Phase 3: sequential loop — no barriers, 1 LDS round-trip per step ----
    const int  pd = w * q + l15;
    const bool vr = (l15 < q) && (pd < P);
    const int  gi = start + (vr ? pd : 0);
    const uint32_t mk = vr ? masks[pd] : 0u;
    float2 ab = *(const float2*)&nodes_abs[(size_t)gi * 2];

    uint32_t* const Grow = &G[(w * 16 + l15) * GSTR];
    const bool h0 = (hi == 0);
    const bool h1 = (hi == 1);

    f32x4 gm[4];
    const f32x4 zero4 = {0.f, 0.f, 0.f, 0.f};
    #pragma unroll
    for (int m = 0; m < 4; ++m) gm[m] = zero4;

    #pragma unroll 1
    for (int f = 0; f < NSTEP; ++f) {
        const float2 c = cxy[f];
        const float mf  = (float)((mk >> f) & 1u);
        const float cxd = ab.x - c.x;
        const float cyd = ab.y - c.y;
        // prefetch next step's coords (row f+1 always exists: S_DIM rows)
        ab = *(const float2*)&nodes_abs[((size_t)(f + 1) * N + gi) * 2];

        // aug B-fragment, K=16 layout (k = 4*hi + e):
        // hi0: {cxd, cxd, cxl, cyd}; hi1: {cyd, cyl, 1, 1}; else 0
        const uint32_t pA = pk_bf16(cxd, cxd);
        const float    cxl = cxd - unbf16(pA & 0xffffu);
        const uint32_t pY = pk_bf16(cyd, cyd);
        const float    cyl = cyd - unbf16(pY & 0xffffu);
        const uint32_t pB = pk_bf16(cxl, cyd);
        const uint32_t pC = pk_bf16(cyd, cyl);
        union { uint32_t u[2]; bf16x4 v; } b2u;
        b2u.u[0] = h0 ? pA : (h1 ? pC : 0u);
        b2u.u[1] = h0 ? pB : (h1 ? 0x3f803f80u : 0u);

        // S_{f-1} B-fragments (bf16 raw gm_sum, words 0..31 of own row)
        const bf16x8 B0 = *(const bf16x8*)&Grow[ 0 + 4*hi];
        const bf16x8 B1 = *(const bf16x8*)&Grow[16 + 4*hi];

        const float invf = __builtin_amdgcn_rcpf((float)(f ? f : 1));   // gm_mean divisor for THIS step
        const float m2 = -2.0f * mf;

        float o0 = 0.0f, o1 = 0.0f;
        #pragma unroll
        for (int m = 0; m < 4; ++m) {
            f32x4 ag = zero4;   // gm_sum @ W_gm part (scaled by invf at combine)
            ag = __builtin_amdgcn_mfma_f32_16x16x32_bf16(agm[m][0], B0, ag, 0, 0, 0);
            ag = __builtin_amdgcn_mfma_f32_16x16x32_bf16(agm[m][1], B1, ag, 0, 0, 0);
            const f32x4 aa = mfma16(aaug[m], b2u.v, zero4);   // coord @ W_in + b_h

            f32x4 h4;
            #pragma unroll
            for (int rr = 0; rr < 4; ++rr) {
                const float x  = fmaf(ag[rr], invf, aa[rr]);
                const float e  = __expf(2.0f * x);
                const float tt = __builtin_amdgcn_rcpf(e + 1.0f);
                h4[rr] = fmaf(tt, m2, mf);          // mf * tanh(x)
                o0 = fmaf(h4[rr], asf(wopk[m][rr] << 16),         o0);
                o1 = fmaf(h4[rr], asf(wopk[m][rr] & 0xffff0000u), o1);
            }
            gm[m] += h4;
            // write S_f (raw gm_sum, bf16) — the ONLY next-step dependency
            const uint32_t p0 = pk_bf16(gm[m][0], gm[m][1]);
            const uint32_t p1 = pk_bf16(gm[m][2], gm[m][3]);
            *(uint2*)&Grow[8*m + 2*hi] = make_uint2(p0, p1);
        }

        // out = (h @ W_out + b_out) * mf — fp32 h, off the critical path
        o0 += __shfl_xor(o0, 16, 64);  o0 += __shfl_xor(o0, 32, 64);
        o1 += __shfl_xor(o1, 16, 64);  o1 += __shfl_xor(o1, 32, 64);
        if (h0 && vr) {
            float2 o;
            o.x = (o0 + bo0) * mf;
            o.y = (o1 + bo1) * mf;
            *(float2*)&out[((size_t)f * N + gi) * 2] = o;
        }
    }

    // ---- final step S-1: zeros ----
    if (t < P) {
        const size_t o = ((size_t)(S_DIM - 1) * N + start + t) * 2;
        out[o] = 0.0f; out[o + 1] = 0.0f;
    }
}

extern "C" void kernel_launch(void* const* d_in, const int* in_sizes, int n_in,
                              void* d_out, int out_size, void* d_ws, size_t ws_size,
                              hipStream_t stream) {
    const float* nodes_abs = (const float*)d_in[0];
    const float* seq_list  = (const float*)d_in[3];
    const int*   pednum    = (const int*)  d_in[5];
    const float* W_in      = (const float*)d_in[6];
    const float* W_gm      = (const float*)d_in[7];
    const float* b_h       = (const float*)d_in[8];
    const float* W_out     = (const float*)d_in[9];
    const float* b_out     = (const float*)d_in[10];
    float*       out       = (float*)d_out;

    const int N = in_sizes[3] / S_DIM;
    const int B = in_sizes[5];

    pfa_kernel<<<B, 512, 0, stream>>>(nodes_abs, seq_list, pednum,
                                      W_in, W_gm, b_h, W_out, b_out,
                                      out, N, B);
}